// Round 1
// 1315.764 us; speedup vs baseline: 1.0328x; 1.0328x over previous
//
#include <hip/hip_runtime.h>

typedef _Float16 f16;
typedef _Float16 f16x8 __attribute__((ext_vector_type(8)));
typedef float f32x4 __attribute__((ext_vector_type(4)));

#define MFMA(a,b,c) __builtin_amdgcn_mfma_f32_16x16x32_f16(a,b,c,0,0,0)

constexpr int B_ = 2048, V_ = 128, EGO_ = 15, H_ = 256;
constexpr int MT = 16;           // batch rows per group
constexpr int ENC_KT = 9;        // K = 288 = 256(h) + 32(x padded); kt 0-3 own, 4-7 partner, 8 x
constexpr int DEC_KT = 8;        // K = 256; kt 0-3 own, 4-7 partner
constexpr int HSTR = 168;        // f16 row stride: [0,128) own h, [128,160) x+pad (336B, 16B-aligned)
constexpr int DSTR = 136;        // f16 row stride: [0,128) own h (272B, 16B-aligned)

// JOURNAL: R3 pair-split passed; R8 = CU-resident weights (RF+LDS). R9 (this):
// split K into own/partner phases; per-wave flags + overlapped poll (probe at
// loop top); partner half read straight into A-frags (dwordx4 sc0 sc1, no LDS
// bounce); 16B write-through exchange stores (was 4x4B -> 8x sector bloat);
// x double-prefetch; 5 barriers/step -> 2; early-exit at per-pair max length
// (decoder pi out delayed one step + zero-fill epilogue).

__device__ __forceinline__ float sigf(float x){ return 1.f/(1.f+__expf(-x)); }
__device__ __forceinline__ float tanh_fast(float x){ return 1.f - 2.f/(1.f+__expf(2.f*x)); }

// relaxed agent-scope ops: coherent bypass, no cache-wide maintenance.
// RULE: cross-block data written via bypass stores MUST be read via bypass loads.
__device__ __forceinline__ void st_u32(uint32_t* p, uint32_t v){
    __hip_atomic_store(p, v, __ATOMIC_RELAXED, __HIP_MEMORY_SCOPE_AGENT);
}
__device__ __forceinline__ uint32_t ld_u32(const uint32_t* p){
    return __hip_atomic_load(p, __ATOMIC_RELAXED, __HIP_MEMORY_SCOPE_AGENT);
}
// single-block 4x16B bypass load + internal drain: outputs valid at asm exit
// (no split-wait copy hazard). early-clobber so dests can't alias addr pairs.
__device__ __forceinline__ void bypass_ld4(f16x8& d0, f16x8& d1, f16x8& d2, f16x8& d3,
                                           const f16* p0, const f16* p1,
                                           const f16* p2, const f16* p3){
    asm volatile(
        "global_load_dwordx4 %0, %4, off sc0 sc1\n\t"
        "global_load_dwordx4 %1, %5, off sc0 sc1\n\t"
        "global_load_dwordx4 %2, %6, off sc0 sc1\n\t"
        "global_load_dwordx4 %3, %7, off sc0 sc1\n\t"
        "s_waitcnt vmcnt(0)"
        : "=&v"(d0), "=&v"(d1), "=&v"(d2), "=&v"(d3)
        : "v"(p0), "v"(p1), "v"(p2), "v"(p3)
        : "memory");
}
__device__ __forceinline__ void bypass_st(f16* p, f16x8 v){
    asm volatile("global_store_dwordx4 %0, %1, off sc0 sc1" :: "v"(p), "v"(v) : "memory");
}
__device__ __forceinline__ void vm_drain(){
    asm volatile("s_waitcnt vmcnt(0)" ::: "memory");
}

// ---- prepack: weights -> per-(hb,wave) MFMA B-fragment order, K permuted so
// kt 0..3 = own half (hb*128..), kt 4..7 = partner half, kt 8 = x (enc only).
__global__ void prepack_enc(const float* __restrict__ Whh1, const float* __restrict__ Wih1,
                            f16* __restrict__ dst){
    int id = blockIdx.x*256 + threadIdx.x;
    if (id >= 2*4*8*ENC_KT*64) return;
    int L = id & 63; int c = id >> 6;
    int kt = c % ENC_KT; c /= ENC_KT;
    int nt = c & 7; c >>= 3;
    int w = c & 3; int hb = c >> 2;
    int n = (nt>>1)*256 + hb*128 + w*32 + (nt&1)*16 + (L&15);
    int kb = (L>>4)*8;
    #pragma unroll
    for (int j=0;j<8;++j){
        int kin = kb + j;
        int k;
        if (kt < 4)      k = hb*128 + kt*32 + kin;
        else if (kt < 8) k = (1-hb)*128 + (kt-4)*32 + kin;
        else             k = 256 + kin;
        float x = (k < 256) ? Whh1[n*256 + k] : ((k < 271) ? Wih1[n*15 + (k-256)] : 0.f);
        dst[(size_t)id*8 + j] = (f16)x;
    }
}
__global__ void prepack_dec(const float* __restrict__ Whh2, f16* __restrict__ dst){
    int id = blockIdx.x*256 + threadIdx.x;
    if (id >= 2*4*8*DEC_KT*64) return;
    int L = id & 63; int c = id >> 6;
    int kt = c % DEC_KT; c /= DEC_KT;
    int nt = c & 7; c >>= 3;
    int w = c & 3; int hb = c >> 2;
    int n = (nt>>1)*256 + hb*128 + w*32 + (nt&1)*16 + (L&15);
    int kb = (L>>4)*8;
    #pragma unroll
    for (int j=0;j<8;++j){
        int kin = kb + j;
        int k = (kt < 4) ? (hb*128 + kt*32 + kin) : ((1-hb)*128 + (kt-4)*32 + kin);
        dst[(size_t)id*8 + j] = (f16)Whh2[n*256 + k];
    }
}
__global__ void bias_kernel(const float* bih1,const float* bhh1,const float* bih2,
                            const float* bhh2,float* be,float* bd){
    int i = blockIdx.x*256 + threadIdx.x;
    if (i < 1024){ be[i]=bih1[i]+bhh1[i]; bd[i]=bih2[i]+bhh2[i]; }
}
__global__ void convert_kernel(const float* __restrict__ src, f16* __restrict__ dst, int n){
    int i = blockIdx.x*256 + threadIdx.x;
    if (i < n) dst[i] = (f16)src[i];
}

// ---- encoder: 256 blocks (pair i <-> i^128), weights CU-resident (RF+LDS) ----
__global__ __launch_bounds__(256,1) void encoder_kernel(
    const float* __restrict__ state, const int* __restrict__ lengths,
    const f16* __restrict__ Wp, const float* __restrict__ bias,
    f16* __restrict__ henc, f16* __restrict__ ebuf, int* __restrict__ flags)
{
    __shared__ __align__(16) f16 wlds[4*8*4*64*8];   // 128 KB: partner-half kts
    __shared__ __align__(16) f16 hcat[MT*HSTR];
    __shared__ int lmax_s;
    const int tid = threadIdx.x;
    const int wave = tid>>6, lane = tid&63, lr = lane&15, quad = lane>>4;
    const int bid = blockIdx.x, hb = bid>>7, g = bid&127, pbid = bid^128;
    const int row0 = g*MT;
    const int xr = tid>>4, xc = tid&15;   // exchange: wave w owns rows 4w..4w+3

    for (int i=tid;i<MT*HSTR;i+=256) hcat[i] = (f16)0.f;
    if (tid < 64){
        int l = (lane<16) ? lengths[row0+lane] : 0;
        #pragma unroll
        for (int m=1;m<16;m<<=1){ int o = __shfl_xor(l, m, 64); l = (o>l)?o:l; }
        if (lane==0) lmax_s = l;
    }

    int len_r[4];
    #pragma unroll
    for (int r=0;r<4;++r) len_r[r] = lengths[row0 + quad*4 + r];

    float bias_v[8];
    #pragma unroll
    for (int nt=0;nt<8;++nt)
        bias_v[nt] = bias[(nt>>1)*256 + hb*128 + wave*32 + (nt&1)*16 + lr];

    const f16x8* Wb = (const f16x8*)Wp + (size_t)((hb*4+wave)*8*ENC_KT)*64;
    // RF: own-half kts 0..3 + x kt 8 -> 160 VGPRs
    f16x8 wreg[8][5];
    #pragma unroll
    for (int nt=0;nt<8;++nt){
        #pragma unroll
        for (int kt=0;kt<4;++kt) wreg[nt][kt] = Wb[(nt*ENC_KT + kt)*64 + lane];
        wreg[nt][4] = Wb[(nt*ENC_KT + 8)*64 + lane];
    }
    // LDS: partner-half kts 4..7 -> wave-private 32 KB slice
    f16x8* wl = (f16x8*)wlds + (size_t)wave*(8*4*64);
    #pragma unroll
    for (int nt=0;nt<8;++nt)
        #pragma unroll
        for (int p=0;p<4;++p)
            wl[(nt*4 + p)*64 + lane] = Wb[(nt*ENC_KT + 4 + p)*64 + lane];

    __syncthreads();                         // zero-init done before x staging
    const int rr = tid/15, cc = tid - rr*15;
    const size_t xbase = (size_t)(row0+rr)*V_*EGO_ + cc;
    float xreg = 0.f;
    if (tid < 240){
        hcat[rr*HSTR + 128 + cc] = (f16)state[xbase];   // stage x_0
        xreg = state[xbase + EGO_];                      // prefetch x_1
    }
    float c_reg[8], h_reg[8];
    #pragma unroll
    for (int i=0;i<8;++i){ c_reg[i]=0.f; h_reg[i]=0.f; }
    __syncthreads();                         // x_0 + lmax visible
    const int Lmax = lmax_s;

    for (int t=0;t<Lmax;++t){
        uint32_t f0 = (uint32_t)t;           // early probe: latency hides under phase-1
        if (t > 0 && lane < 4) f0 = ld_u32((const uint32_t*)&flags[pbid*4 + lane]);
        f32x4 acc[8];
        #pragma unroll
        for (int nt=0;nt<8;++nt) acc[nt] = (f32x4){bias_v[nt],bias_v[nt],bias_v[nt],bias_v[nt]};
        // phase 1: own half + x (RF weights, local hcat)
        #pragma unroll
        for (int kt=0;kt<4;++kt){
            f16x8 a = *(const f16x8*)&hcat[lr*HSTR + kt*32 + quad*8];
            #pragma unroll
            for (int nt=0;nt<8;++nt) acc[nt] = MFMA(a, wreg[nt][kt], acc[nt]);
        }
        {
            f16x8 a = *(const f16x8*)&hcat[lr*HSTR + 128 + quad*8];
            #pragma unroll
            for (int nt=0;nt<8;++nt) acc[nt] = MFMA(a, wreg[nt][4], acc[nt]);
        }
        // phase 2: partner half, straight from ebuf into A-frags
        if (t > 0){
            f16x8 b0[8];
            #pragma unroll
            for (int nt=0;nt<8;++nt) b0[nt] = wl[(nt*4 + 0)*64 + lane];
            if (lane < 4){
                while (f0 < (uint32_t)t){
                    __builtin_amdgcn_s_sleep(1);
                    f0 = ld_u32((const uint32_t*)&flags[pbid*4 + lane]);
                }
            }
            const f16* src = ebuf + ((size_t)((t-1)&1)*256 + pbid)*2048 + lr*128 + quad*8;
            f16x8 a0,a1,a2,a3;
            bypass_ld4(a0,a1,a2,a3, src, src+32, src+64, src+96);
            #pragma unroll
            for (int nt=0;nt<8;++nt) acc[nt] = MFMA(a0, b0[nt], acc[nt]);
            #pragma unroll
            for (int nt=0;nt<8;++nt) acc[nt] = MFMA(a1, wl[(nt*4+1)*64+lane], acc[nt]);
            #pragma unroll
            for (int nt=0;nt<8;++nt) acc[nt] = MFMA(a2, wl[(nt*4+2)*64+lane], acc[nt]);
            #pragma unroll
            for (int nt=0;nt<8;++nt) acc[nt] = MFMA(a3, wl[(nt*4+3)*64+lane], acc[nt]);
        }
        __syncthreads();                     // B2: phase-1 reads done before overwrite
        #pragma unroll
        for (int s=0;s<2;++s){
            #pragma unroll
            for (int r=0;r<4;++r){
                int idx = s*4 + r;
                float gi = acc[s][r],   gf = acc[2+s][r];
                float gg = acc[4+s][r], go = acc[6+s][r];
                float cn = sigf(gf)*c_reg[idx] + sigf(gi)*tanh_fast(gg);
                float hn = sigf(go)*tanh_fast(cn);
                bool upd = (t < len_r[r]);
                c_reg[idx] = upd ? cn : c_reg[idx];
                h_reg[idx] = upd ? hn : h_reg[idx];
                hcat[(quad*4+r)*HSTR + wave*32 + s*16 + lr] = (f16)h_reg[idx];
            }
        }
        if (tid < 240) hcat[rr*HSTR + 128 + cc] = (f16)xreg;   // stage x_{t+1}
        __syncthreads();                     // B3: h_t + x_{t+1} visible
        {   // push own half, row-major [16][128] so partner loads frags directly
            f16x8 h8 = *(const f16x8*)&hcat[xr*HSTR + xc*8];
            f16* dst = ebuf + ((size_t)(t&1)*256 + bid)*2048 + xr*128 + xc*8;
            bypass_st(dst, h8);
        }
        vm_drain();                          // per-wave: stores at coherence pt
        if (lane == 0) st_u32((uint32_t*)&flags[bid*4 + wave], (uint32_t)(t+1));
        if (tid < 240){                      // prefetch x_{t+2} (post-flag, off crit path)
            int tn = (t+2 < V_) ? (t+2) : (V_-1);
            xreg = state[xbase + (size_t)tn*EGO_];
        }
    }
    #pragma unroll
    for (int s=0;s<2;++s)
        #pragma unroll
        for (int r=0;r<4;++r)
            henc[(size_t)(row0+quad*4+r)*H_ + hb*128 + wave*32 + s*16 + lr] = (f16)h_reg[s*4+r];
}

// ---- generic GEMM: C = act(A[M,K] @ W[N,K]^T + bias) ----
template<bool RELU, bool F32OUT>
__global__ __launch_bounds__(256,2) void gemm_kernel(
    const f16* __restrict__ A, const f16* __restrict__ W,
    const float* __restrict__ bias, void* __restrict__ outp,
    int M, int N, int K)
{
    constexpr int ASTR = 40;
    __shared__ __align__(16) f16 As[64*ASTR];
    __shared__ __align__(16) f16 Ws[64*ASTR];
    const int tid = threadIdx.x;
    const int wave = tid>>6, lane = tid&63, lr = lane&15, quad = lane>>4;
    const int n0 = blockIdx.x*64, m0 = blockIdx.y*64;
    const int lrow = tid>>2, lk8 = (tid&3)*8;

    f32x4 acc[4];
    #pragma unroll
    for (int mt=0;mt<4;++mt) acc[mt] = (f32x4){0.f,0.f,0.f,0.f};

    for (int k0=0;k0<K;k0+=32){
        __syncthreads();
        *(f16x8*)&As[lrow*ASTR + lk8] = *(const f16x8*)&A[(size_t)(m0+lrow)*K + k0 + lk8];
        *(f16x8*)&Ws[lrow*ASTR + lk8] = *(const f16x8*)&W[(size_t)(n0+lrow)*K + k0 + lk8];
        __syncthreads();
        f16x8 b = *(const f16x8*)&Ws[(wave*16+lr)*ASTR + quad*8];
        #pragma unroll
        for (int mt=0;mt<4;++mt){
            f16x8 a = *(const f16x8*)&As[(mt*16+lr)*ASTR + quad*8];
            acc[mt] = MFMA(a, b, acc[mt]);
        }
    }
    float bv = bias[n0 + wave*16 + lr];
    #pragma unroll
    for (int mt=0;mt<4;++mt){
        #pragma unroll
        for (int r=0;r<4;++r){
            float v = acc[mt][r] + bv;
            if (RELU) v = fmaxf(v, 0.f);
            int m = m0 + mt*16 + quad*4 + r, n = n0 + wave*16 + lr;
            if (F32OUT) ((float*)outp)[(size_t)m*N + n] = v;
            else        ((f16*)outp)[(size_t)m*N + n] = (f16)v;
        }
    }
}

// ---- decoder: pair-split, CU-resident weights, fused pi head (out delayed 1 step) ----
__global__ __launch_bounds__(256,1) void decoder_kernel(
    const int* __restrict__ lengths, const f16* __restrict__ Wp,
    const float* __restrict__ xdec, const float* __restrict__ Wpi,
    const float* __restrict__ bpi, float* __restrict__ out,
    f16* __restrict__ ebuf, int* __restrict__ flags, float* __restrict__ pbuf)
{
    __shared__ __align__(16) f16 wlds[4*8*4*64*8];   // 128 KB
    __shared__ __align__(16) f16 hbuf[MT*DSTR];
    __shared__ float part[4][16][2];
    __shared__ int lmax_s;
    const int tid = threadIdx.x;
    const int wave = tid>>6, lane = tid&63, lr = lane&15, quad = lane>>4;
    const int bid = blockIdx.x, hb = bid>>7, g = bid&127, pbid = bid^128;
    const int row0 = g*MT;
    const int xr = tid>>4, xc = tid&15;

    for (int i=tid;i<MT*DSTR;i+=256) hbuf[i] = (f16)0.f;
    if (tid < 64){
        int l = (lane<16) ? lengths[row0+lane] : 0;
        #pragma unroll
        for (int m=1;m<16;m<<=1){ int o = __shfl_xor(l, m, 64); l = (o>l)?o:l; }
        if (lane==0) lmax_s = l;
    }

    float xd[8][4];
    #pragma unroll
    for (int nt=0;nt<8;++nt){
        int n = (nt>>1)*256 + hb*128 + wave*32 + (nt&1)*16 + lr;
        #pragma unroll
        for (int r=0;r<4;++r) xd[nt][r] = xdec[(size_t)(row0+quad*4+r)*1024 + n];
    }
    float wpi_reg[2][2];
    #pragma unroll
    for (int a=0;a<2;++a)
        #pragma unroll
        for (int s=0;s<2;++s)
            wpi_reg[a][s] = Wpi[a*H_ + hb*128 + wave*32 + s*16 + lr];

    const f16x8* Wb = (const f16x8*)Wp + (size_t)((hb*4+wave)*8*DEC_KT)*64;
    f16x8 wreg[8][4];                        // own-half kts 0..3
    #pragma unroll
    for (int nt=0;nt<8;++nt)
        #pragma unroll
        for (int kt=0;kt<4;++kt)
            wreg[nt][kt] = Wb[(nt*DEC_KT + kt)*64 + lane];
    f16x8* wl = (f16x8*)wlds + (size_t)wave*(8*4*64);
    #pragma unroll
    for (int nt=0;nt<8;++nt)
        #pragma unroll
        for (int p=0;p<4;++p)
            wl[(nt*4 + p)*64 + lane] = Wb[(nt*DEC_KT + 4 + p)*64 + lane];

    float c_reg[8];
    #pragma unroll
    for (int i=0;i<8;++i) c_reg[i]=0.f;

    const int m_o = (tid>>1)&15, a_o = tid&1;
    const float bpi_o = bpi[a_o];
    const int len_o = (tid<32) ? lengths[row0+m_o] : 0;
    const size_t outbase = (size_t)(row0+m_o)*V_*2 + a_o;
    float own_prev = 0.f;

    __syncthreads();
    const int Lmax = lmax_s;

    for (int t=0;t<Lmax;++t){
        uint32_t f0 = (uint32_t)t;
        if (t > 0 && lane < 4) f0 = ld_u32((const uint32_t*)&flags[pbid*4 + lane]);
        f32x4 acc[8];
        #pragma unroll
        for (int nt=0;nt<8;++nt) acc[nt] = (f32x4){xd[nt][0],xd[nt][1],xd[nt][2],xd[nt][3]};
        #pragma unroll
        for (int kt=0;kt<4;++kt){
            f16x8 a = *(const f16x8*)&hbuf[lr*DSTR + kt*32 + quad*8];
            #pragma unroll
            for (int nt=0;nt<8;++nt) acc[nt] = MFMA(a, wreg[nt][kt], acc[nt]);
        }
        if (t > 0){
            f16x8 b0[8];
            #pragma unroll
            for (int nt=0;nt<8;++nt) b0[nt] = wl[(nt*4 + 0)*64 + lane];
            if (lane < 4){
                while (f0 < (uint32_t)t){
                    __builtin_amdgcn_s_sleep(1);
                    f0 = ld_u32((const uint32_t*)&flags[pbid*4 + lane]);
                }
            }
            const f16* src = ebuf + ((size_t)((t-1)&1)*256 + pbid)*2048 + lr*128 + quad*8;
            f16x8 a0,a1,a2,a3;
            bypass_ld4(a0,a1,a2,a3, src, src+32, src+64, src+96);
            #pragma unroll
            for (int nt=0;nt<8;++nt) acc[nt] = MFMA(a0, b0[nt], acc[nt]);
            #pragma unroll
            for (int nt=0;nt<8;++nt) acc[nt] = MFMA(a1, wl[(nt*4+1)*64+lane], acc[nt]);
            #pragma unroll
            for (int nt=0;nt<8;++nt) acc[nt] = MFMA(a2, wl[(nt*4+2)*64+lane], acc[nt]);
            #pragma unroll
            for (int nt=0;nt<8;++nt) acc[nt] = MFMA(a3, wl[(nt*4+3)*64+lane], acc[nt]);
            // delayed pi output for step t-1 (partner partials valid under flag>=t)
            if (hb == 0 && tid < 32){
                uint32_t pu = ld_u32((const uint32_t*)pbuf + ((size_t)((t-1)&1)*128 + g)*32 + tid);
                float v = own_prev + __uint_as_float(pu) + bpi_o;
                v = tanh_fast(v);
                out[outbase + (size_t)(t-1)*2] = ((t-1) < len_o) ? v : 0.f;
            }
        }
        __syncthreads();                     // B2
        float spi[4][2];
        #pragma unroll
        for (int r=0;r<4;++r){ spi[r][0]=0.f; spi[r][1]=0.f; }
        #pragma unroll
        for (int s=0;s<2;++s){
            #pragma unroll
            for (int r=0;r<4;++r){
                int idx = s*4 + r;
                float gi = acc[s][r],   gf = acc[2+s][r];
                float gg = acc[4+s][r], go = acc[6+s][r];
                float cn = sigf(gf)*c_reg[idx] + sigf(gi)*tanh_fast(gg);
                c_reg[idx] = cn;
                float hn = sigf(go)*tanh_fast(cn);
                hbuf[(quad*4+r)*DSTR + wave*32 + s*16 + lr] = (f16)hn;
                spi[r][0] += cn*wpi_reg[0][s];
                spi[r][1] += cn*wpi_reg[1][s];
            }
        }
        #pragma unroll
        for (int msk=1; msk<16; msk<<=1){
            #pragma unroll
            for (int r=0;r<4;++r){
                spi[r][0] += __shfl_xor(spi[r][0], msk, 64);
                spi[r][1] += __shfl_xor(spi[r][1], msk, 64);
            }
        }
        if (lr == 0){
            #pragma unroll
            for (int r=0;r<4;++r){
                part[wave][quad*4+r][0] = spi[r][0];
                part[wave][quad*4+r][1] = spi[r][1];
            }
        }
        __syncthreads();                     // B3: h_t + part visible
        {
            f16x8 h8 = *(const f16x8*)&hbuf[xr*DSTR + xc*8];
            f16* dst = ebuf + ((size_t)(t&1)*256 + bid)*2048 + xr*128 + xc*8;
            bypass_st(dst, h8);
        }
        if (tid < 32){
            float own4 = part[0][m_o][a_o]+part[1][m_o][a_o]+part[2][m_o][a_o]+part[3][m_o][a_o];
            if (hb == 1) st_u32((uint32_t*)pbuf + ((size_t)(t&1)*128 + g)*32 + tid,
                                __float_as_uint(own4));
            else         own_prev = own4;
        }
        vm_drain();                          // per-wave: ebuf(+pbuf) at coherence pt
        if (lane == 0) st_u32((uint32_t*)&flags[bid*4 + wave], (uint32_t)(t+1));
    }
    // epilogue: final pi output (step Lmax-1) + zero-fill t >= Lmax
    if (hb == 0 && tid < 32){
        uint32_t fv = ld_u32((const uint32_t*)&flags[pbid*4 + 0]);
        while (fv < (uint32_t)Lmax){
            __builtin_amdgcn_s_sleep(1);
            fv = ld_u32((const uint32_t*)&flags[pbid*4 + 0]);
        }
        uint32_t pu = ld_u32((const uint32_t*)pbuf + ((size_t)((Lmax-1)&1)*128 + g)*32 + tid);
        float v = own_prev + __uint_as_float(pu) + bpi_o;
        v = tanh_fast(v);
        out[outbase + (size_t)(Lmax-1)*2] = ((Lmax-1) < len_o) ? v : 0.f;
        for (int t=Lmax; t<V_; ++t) out[outbase + (size_t)t*2] = 0.f;
    }
}

extern "C" void kernel_launch(void* const* d_in, const int* in_sizes, int n_in,
                              void* d_out, int out_size, void* d_ws, size_t ws_size,
                              hipStream_t stream) {
    const float* state = (const float*)d_in[0];
    const int*   lengths=(const int*)d_in[1];
    const float* Wih1 = (const float*)d_in[2];
    const float* Whh1 = (const float*)d_in[3];
    const float* bih1 = (const float*)d_in[4];
    const float* bhh1 = (const float*)d_in[5];
    const float* W1   = (const float*)d_in[6];  const float* b1 = (const float*)d_in[7];
    const float* W2   = (const float*)d_in[8];  const float* b2 = (const float*)d_in[9];
    const float* W3   = (const float*)d_in[10]; const float* b3 = (const float*)d_in[11];
    const float* W4   = (const float*)d_in[12]; const float* b4 = (const float*)d_in[13];
    const float* Wih2 = (const float*)d_in[14]; const float* Whh2=(const float*)d_in[15];
    const float* bih2 = (const float*)d_in[16]; const float* bhh2=(const float*)d_in[17];
    const float* Wpi  = (const float*)d_in[18]; const float* bpi =(const float*)d_in[19];
    float* out = (float*)d_out;

    char* p = (char*)d_ws;
    auto alloc = [&](size_t bytes){ char* r = p; p += (bytes + 255) & ~(size_t)255; return r; };
    f16* WencP   = (f16*)alloc((size_t)2*4*8*ENC_KT*64*8*2);
    f16* WdecP   = (f16*)alloc((size_t)2*4*8*DEC_KT*64*8*2);
    f16* W1f     = (f16*)alloc((size_t)1024*256*2);
    f16* W2f     = (f16*)alloc((size_t)1024*1024*2);
    f16* W3f     = (f16*)alloc((size_t)512*1024*2);
    f16* W4f     = (f16*)alloc((size_t)256*512*2);
    f16* Wih2f   = (f16*)alloc((size_t)1024*256*2);
    float* biasE = (float*)alloc(1024*4);
    float* biasD = (float*)alloc(1024*4);
    f16* henc    = (f16*)alloc((size_t)2048*256*2);
    f16* act1    = (f16*)alloc((size_t)2048*1024*2);
    f16* act2    = (f16*)alloc((size_t)2048*1024*2);
    f16* act3    = (f16*)alloc((size_t)2048*512*2);
    f16* x4      = (f16*)alloc((size_t)2048*256*2);
    float* xdec  = (float*)alloc((size_t)2048*1024*4);
    f16* ebuf    = (f16*)alloc((size_t)2*256*2048*2);
    float* pbuf  = (float*)alloc((size_t)2*128*32*4);
    int* flags   = (int*)alloc((size_t)2048*4);   // [0:1024)=enc, [1024:2048)=dec (4 per block)

    hipMemsetAsync(flags, 0, 2048*4, stream);

    prepack_enc<<<(2*4*8*ENC_KT*64+255)/256,256,0,stream>>>(Whh1, Wih1, WencP);
    prepack_dec<<<(2*4*8*DEC_KT*64+255)/256,256,0,stream>>>(Whh2, WdecP);
    bias_kernel<<<4,256,0,stream>>>(bih1,bhh1,bih2,bhh2,biasE,biasD);
    convert_kernel<<<(1024*256+255)/256,256,0,stream>>>(W1, W1f, 1024*256);
    convert_kernel<<<(1024*1024+255)/256,256,0,stream>>>(W2, W2f, 1024*1024);
    convert_kernel<<<(512*1024+255)/256,256,0,stream>>>(W3, W3f, 512*1024);
    convert_kernel<<<(256*512+255)/256,256,0,stream>>>(W4, W4f, 256*512);
    convert_kernel<<<(1024*256+255)/256,256,0,stream>>>(Wih2, Wih2f, 1024*256);

    encoder_kernel<<<256,256,0,stream>>>(state, lengths, WencP, biasE, henc, ebuf, flags);

    gemm_kernel<true ,false><<<dim3(16,32),256,0,stream>>>(henc, W1f, b1, act1, 2048,1024,256);
    gemm_kernel<true ,false><<<dim3(16,32),256,0,stream>>>(act1, W2f, b2, act2, 2048,1024,1024);
    gemm_kernel<true ,false><<<dim3( 8,32),256,0,stream>>>(act2, W3f, b3, act3, 2048, 512,1024);
    gemm_kernel<true ,false><<<dim3( 4,32),256,0,stream>>>(act3, W4f, b4, x4,   2048, 256, 512);
    gemm_kernel<false,true ><<<dim3(16,32),256,0,stream>>>(x4, Wih2f, biasD, xdec, 2048,1024,256);

    decoder_kernel<<<256,256,0,stream>>>(lengths, WdecP, xdec, Wpi, bpi, out,
                                         ebuf, flags+1024, pbuf);
}

// Round 2
// 1281.998 us; speedup vs baseline: 1.0600x; 1.0263x over previous
//
#include <hip/hip_runtime.h>

typedef _Float16 f16;
typedef _Float16 f16x8 __attribute__((ext_vector_type(8)));
typedef float f32x4 __attribute__((ext_vector_type(4)));

#define MFMA(a,b,c) __builtin_amdgcn_mfma_f32_16x16x32_f16(a,b,c,0,0,0)

constexpr int B_ = 2048, V_ = 128, EGO_ = 15, H_ = 256;
constexpr int MT = 16;           // batch rows per group
constexpr int ENC_KT = 9;        // K = 288 = 256(h) + 32(x padded); kt 0-3 own, 4-7 partner, 8 x
constexpr int DEC_KT = 8;        // K = 256; kt 0-3 own, 4-7 partner
constexpr int HSTR = 168;        // f16 row stride: [0,128) own h, [128,160) x+pad (336B, 16B-aligned)
constexpr int DSTR = 136;        // f16 row stride: [0,128) own h (272B, 16B-aligned)

// JOURNAL: R3 pair-split passed; R8 = CU-resident weights (RF+LDS); R9 = K
// own/partner phase split, per-wave flags, direct-to-frag exchange loads, 16B
// exchange stores, 2 barriers/step, early-exit (passed, 1316us, but decoder
// REGRESSED to 617us). R10 (this): R9's asm used "sc0 sc1" = SYSTEM scope ->
// every exchange op round-tripped to HBM (WRITE_SIZE 132MB = 2x payload,
// FETCH 72MB = ebuf misses). Fix: "sc1" only = device/agent scope, coherence
// point = Infinity Cache, same as the proven __hip_atomic AGENT path.

__device__ __forceinline__ float sigf(float x){ return 1.f/(1.f+__expf(-x)); }
__device__ __forceinline__ float tanh_fast(float x){ return 1.f - 2.f/(1.f+__expf(2.f*x)); }

// relaxed agent-scope ops: coherent bypass of L1 (and local L2 for remote
// visibility), served at LLC. RULE: cross-block data written via bypass stores
// MUST be read via bypass loads (stale-L1 bug, R5). Scope rule (R10): sc1 only
// = device scope (LLC). sc0 sc1 = system scope (HBM) -- never use for
// device-internal exchange.
__device__ __forceinline__ void st_u32(uint32_t* p, uint32_t v){
    __hip_atomic_store(p, v, __ATOMIC_RELAXED, __HIP_MEMORY_SCOPE_AGENT);
}
__device__ __forceinline__ uint32_t ld_u32(const uint32_t* p){
    return __hip_atomic_load(p, __ATOMIC_RELAXED, __HIP_MEMORY_SCOPE_AGENT);
}
// single-block 4x16B device-scope load + internal drain: outputs valid at asm
// exit (no split-wait copy hazard). early-clobber so dests can't alias addrs.
__device__ __forceinline__ void bypass_ld4(f16x8& d0, f16x8& d1, f16x8& d2, f16x8& d3,
                                           const f16* p0, const f16* p1,
                                           const f16* p2, const f16* p3){
    asm volatile(
        "global_load_dwordx4 %0, %4, off sc1\n\t"
        "global_load_dwordx4 %1, %5, off sc1\n\t"
        "global_load_dwordx4 %2, %6, off sc1\n\t"
        "global_load_dwordx4 %3, %7, off sc1\n\t"
        "s_waitcnt vmcnt(0)"
        : "=&v"(d0), "=&v"(d1), "=&v"(d2), "=&v"(d3)
        : "v"(p0), "v"(p1), "v"(p2), "v"(p3)
        : "memory");
}
__device__ __forceinline__ void bypass_st(f16* p, f16x8 v){
    asm volatile("global_store_dwordx4 %0, %1, off sc1" :: "v"(p), "v"(v) : "memory");
}
__device__ __forceinline__ void vm_drain(){
    asm volatile("s_waitcnt vmcnt(0)" ::: "memory");
}

// ---- prepack: weights -> per-(hb,wave) MFMA B-fragment order, K permuted so
// kt 0..3 = own half (hb*128..), kt 4..7 = partner half, kt 8 = x (enc only).
__global__ void prepack_enc(const float* __restrict__ Whh1, const float* __restrict__ Wih1,
                            f16* __restrict__ dst){
    int id = blockIdx.x*256 + threadIdx.x;
    if (id >= 2*4*8*ENC_KT*64) return;
    int L = id & 63; int c = id >> 6;
    int kt = c % ENC_KT; c /= ENC_KT;
    int nt = c & 7; c >>= 3;
    int w = c & 3; int hb = c >> 2;
    int n = (nt>>1)*256 + hb*128 + w*32 + (nt&1)*16 + (L&15);
    int kb = (L>>4)*8;
    #pragma unroll
    for (int j=0;j<8;++j){
        int kin = kb + j;
        int k;
        if (kt < 4)      k = hb*128 + kt*32 + kin;
        else if (kt < 8) k = (1-hb)*128 + (kt-4)*32 + kin;
        else             k = 256 + kin;
        float x = (k < 256) ? Whh1[n*256 + k] : ((k < 271) ? Wih1[n*15 + (k-256)] : 0.f);
        dst[(size_t)id*8 + j] = (f16)x;
    }
}
__global__ void prepack_dec(const float* __restrict__ Whh2, f16* __restrict__ dst){
    int id = blockIdx.x*256 + threadIdx.x;
    if (id >= 2*4*8*DEC_KT*64) return;
    int L = id & 63; int c = id >> 6;
    int kt = c % DEC_KT; c /= DEC_KT;
    int nt = c & 7; c >>= 3;
    int w = c & 3; int hb = c >> 2;
    int n = (nt>>1)*256 + hb*128 + w*32 + (nt&1)*16 + (L&15);
    int kb = (L>>4)*8;
    #pragma unroll
    for (int j=0;j<8;++j){
        int kin = kb + j;
        int k = (kt < 4) ? (hb*128 + kt*32 + kin) : ((1-hb)*128 + (kt-4)*32 + kin);
        dst[(size_t)id*8 + j] = (f16)Whh2[n*256 + k];
    }
}
__global__ void bias_kernel(const float* bih1,const float* bhh1,const float* bih2,
                            const float* bhh2,float* be,float* bd){
    int i = blockIdx.x*256 + threadIdx.x;
    if (i < 1024){ be[i]=bih1[i]+bhh1[i]; bd[i]=bih2[i]+bhh2[i]; }
}
__global__ void convert_kernel(const float* __restrict__ src, f16* __restrict__ dst, int n){
    int i = blockIdx.x*256 + threadIdx.x;
    if (i < n) dst[i] = (f16)src[i];
}

// ---- encoder: 256 blocks (pair i <-> i^128), weights CU-resident (RF+LDS) ----
__global__ __launch_bounds__(256,1) void encoder_kernel(
    const float* __restrict__ state, const int* __restrict__ lengths,
    const f16* __restrict__ Wp, const float* __restrict__ bias,
    f16* __restrict__ henc, f16* __restrict__ ebuf, int* __restrict__ flags)
{
    __shared__ __align__(16) f16 wlds[4*8*4*64*8];   // 128 KB: partner-half kts
    __shared__ __align__(16) f16 hcat[MT*HSTR];
    __shared__ int lmax_s;
    const int tid = threadIdx.x;
    const int wave = tid>>6, lane = tid&63, lr = lane&15, quad = lane>>4;
    const int bid = blockIdx.x, hb = bid>>7, g = bid&127, pbid = bid^128;
    const int row0 = g*MT;
    const int xr = tid>>4, xc = tid&15;   // exchange: wave w owns rows 4w..4w+3

    for (int i=tid;i<MT*HSTR;i+=256) hcat[i] = (f16)0.f;
    if (tid < 64){
        int l = (lane<16) ? lengths[row0+lane] : 0;
        #pragma unroll
        for (int m=1;m<16;m<<=1){ int o = __shfl_xor(l, m, 64); l = (o>l)?o:l; }
        if (lane==0) lmax_s = l;
    }

    int len_r[4];
    #pragma unroll
    for (int r=0;r<4;++r) len_r[r] = lengths[row0 + quad*4 + r];

    float bias_v[8];
    #pragma unroll
    for (int nt=0;nt<8;++nt)
        bias_v[nt] = bias[(nt>>1)*256 + hb*128 + wave*32 + (nt&1)*16 + lr];

    const f16x8* Wb = (const f16x8*)Wp + (size_t)((hb*4+wave)*8*ENC_KT)*64;
    // RF: own-half kts 0..3 + x kt 8 -> 160 VGPRs
    f16x8 wreg[8][5];
    #pragma unroll
    for (int nt=0;nt<8;++nt){
        #pragma unroll
        for (int kt=0;kt<4;++kt) wreg[nt][kt] = Wb[(nt*ENC_KT + kt)*64 + lane];
        wreg[nt][4] = Wb[(nt*ENC_KT + 8)*64 + lane];
    }
    // LDS: partner-half kts 4..7 -> wave-private 32 KB slice
    f16x8* wl = (f16x8*)wlds + (size_t)wave*(8*4*64);
    #pragma unroll
    for (int nt=0;nt<8;++nt)
        #pragma unroll
        for (int p=0;p<4;++p)
            wl[(nt*4 + p)*64 + lane] = Wb[(nt*ENC_KT + 4 + p)*64 + lane];

    __syncthreads();                         // zero-init done before x staging
    const int rr = tid/15, cc = tid - rr*15;
    const size_t xbase = (size_t)(row0+rr)*V_*EGO_ + cc;
    float xreg = 0.f;
    if (tid < 240){
        hcat[rr*HSTR + 128 + cc] = (f16)state[xbase];   // stage x_0
        xreg = state[xbase + EGO_];                      // prefetch x_1
    }
    float c_reg[8], h_reg[8];
    #pragma unroll
    for (int i=0;i<8;++i){ c_reg[i]=0.f; h_reg[i]=0.f; }
    __syncthreads();                         // x_0 + lmax visible
    const int Lmax = lmax_s;

    for (int t=0;t<Lmax;++t){
        uint32_t f0 = (uint32_t)t;           // early probe: latency hides under phase-1
        if (t > 0 && lane < 4) f0 = ld_u32((const uint32_t*)&flags[pbid*4 + lane]);
        f32x4 acc[8];
        #pragma unroll
        for (int nt=0;nt<8;++nt) acc[nt] = (f32x4){bias_v[nt],bias_v[nt],bias_v[nt],bias_v[nt]};
        // phase 1: own half + x (RF weights, local hcat)
        #pragma unroll
        for (int kt=0;kt<4;++kt){
            f16x8 a = *(const f16x8*)&hcat[lr*HSTR + kt*32 + quad*8];
            #pragma unroll
            for (int nt=0;nt<8;++nt) acc[nt] = MFMA(a, wreg[nt][kt], acc[nt]);
        }
        {
            f16x8 a = *(const f16x8*)&hcat[lr*HSTR + 128 + quad*8];
            #pragma unroll
            for (int nt=0;nt<8;++nt) acc[nt] = MFMA(a, wreg[nt][4], acc[nt]);
        }
        // phase 2: partner half, straight from ebuf into A-frags
        if (t > 0){
            f16x8 b0[8];
            #pragma unroll
            for (int nt=0;nt<8;++nt) b0[nt] = wl[(nt*4 + 0)*64 + lane];
            if (lane < 4){
                while (f0 < (uint32_t)t){
                    __builtin_amdgcn_s_sleep(1);
                    f0 = ld_u32((const uint32_t*)&flags[pbid*4 + lane]);
                }
            }
            const f16* src = ebuf + ((size_t)((t-1)&1)*256 + pbid)*2048 + lr*128 + quad*8;
            f16x8 a0,a1,a2,a3;
            bypass_ld4(a0,a1,a2,a3, src, src+32, src+64, src+96);
            #pragma unroll
            for (int nt=0;nt<8;++nt) acc[nt] = MFMA(a0, b0[nt], acc[nt]);
            #pragma unroll
            for (int nt=0;nt<8;++nt) acc[nt] = MFMA(a1, wl[(nt*4+1)*64+lane], acc[nt]);
            #pragma unroll
            for (int nt=0;nt<8;++nt) acc[nt] = MFMA(a2, wl[(nt*4+2)*64+lane], acc[nt]);
            #pragma unroll
            for (int nt=0;nt<8;++nt) acc[nt] = MFMA(a3, wl[(nt*4+3)*64+lane], acc[nt]);
        }
        __syncthreads();                     // B2: phase-1 reads done before overwrite
        #pragma unroll
        for (int s=0;s<2;++s){
            #pragma unroll
            for (int r=0;r<4;++r){
                int idx = s*4 + r;
                float gi = acc[s][r],   gf = acc[2+s][r];
                float gg = acc[4+s][r], go = acc[6+s][r];
                float cn = sigf(gf)*c_reg[idx] + sigf(gi)*tanh_fast(gg);
                float hn = sigf(go)*tanh_fast(cn);
                bool upd = (t < len_r[r]);
                c_reg[idx] = upd ? cn : c_reg[idx];
                h_reg[idx] = upd ? hn : h_reg[idx];
                hcat[(quad*4+r)*HSTR + wave*32 + s*16 + lr] = (f16)h_reg[idx];
            }
        }
        if (tid < 240) hcat[rr*HSTR + 128 + cc] = (f16)xreg;   // stage x_{t+1}
        __syncthreads();                     // B3: h_t + x_{t+1} visible
        {   // push own half, row-major [16][128] so partner loads frags directly
            f16x8 h8 = *(const f16x8*)&hcat[xr*HSTR + xc*8];
            f16* dst = ebuf + ((size_t)(t&1)*256 + bid)*2048 + xr*128 + xc*8;
            bypass_st(dst, h8);
        }
        vm_drain();                          // per-wave: stores at coherence pt
        if (lane == 0) st_u32((uint32_t*)&flags[bid*4 + wave], (uint32_t)(t+1));
        if (tid < 240){                      // prefetch x_{t+2} (post-flag, off crit path)
            int tn = (t+2 < V_) ? (t+2) : (V_-1);
            xreg = state[xbase + (size_t)tn*EGO_];
        }
    }
    #pragma unroll
    for (int s=0;s<2;++s)
        #pragma unroll
        for (int r=0;r<4;++r)
            henc[(size_t)(row0+quad*4+r)*H_ + hb*128 + wave*32 + s*16 + lr] = (f16)h_reg[s*4+r];
}

// ---- generic GEMM: C = act(A[M,K] @ W[N,K]^T + bias) ----
template<bool RELU, bool F32OUT>
__global__ __launch_bounds__(256,2) void gemm_kernel(
    const f16* __restrict__ A, const f16* __restrict__ W,
    const float* __restrict__ bias, void* __restrict__ outp,
    int M, int N, int K)
{
    constexpr int ASTR = 40;
    __shared__ __align__(16) f16 As[64*ASTR];
    __shared__ __align__(16) f16 Ws[64*ASTR];
    const int tid = threadIdx.x;
    const int wave = tid>>6, lane = tid&63, lr = lane&15, quad = lane>>4;
    const int n0 = blockIdx.x*64, m0 = blockIdx.y*64;
    const int lrow = tid>>2, lk8 = (tid&3)*8;

    f32x4 acc[4];
    #pragma unroll
    for (int mt=0;mt<4;++mt) acc[mt] = (f32x4){0.f,0.f,0.f,0.f};

    for (int k0=0;k0<K;k0+=32){
        __syncthreads();
        *(f16x8*)&As[lrow*ASTR + lk8] = *(const f16x8*)&A[(size_t)(m0+lrow)*K + k0 + lk8];
        *(f16x8*)&Ws[lrow*ASTR + lk8] = *(const f16x8*)&W[(size_t)(n0+lrow)*K + k0 + lk8];
        __syncthreads();
        f16x8 b = *(const f16x8*)&Ws[(wave*16+lr)*ASTR + quad*8];
        #pragma unroll
        for (int mt=0;mt<4;++mt){
            f16x8 a = *(const f16x8*)&As[(mt*16+lr)*ASTR + quad*8];
            acc[mt] = MFMA(a, b, acc[mt]);
        }
    }
    float bv = bias[n0 + wave*16 + lr];
    #pragma unroll
    for (int mt=0;mt<4;++mt){
        #pragma unroll
        for (int r=0;r<4;++r){
            float v = acc[mt][r] + bv;
            if (RELU) v = fmaxf(v, 0.f);
            int m = m0 + mt*16 + quad*4 + r, n = n0 + wave*16 + lr;
            if (F32OUT) ((float*)outp)[(size_t)m*N + n] = v;
            else        ((f16*)outp)[(size_t)m*N + n] = (f16)v;
        }
    }
}

// ---- decoder: pair-split, CU-resident weights, fused pi head (out delayed 1 step) ----
__global__ __launch_bounds__(256,1) void decoder_kernel(
    const int* __restrict__ lengths, const f16* __restrict__ Wp,
    const float* __restrict__ xdec, const float* __restrict__ Wpi,
    const float* __restrict__ bpi, float* __restrict__ out,
    f16* __restrict__ ebuf, int* __restrict__ flags, float* __restrict__ pbuf)
{
    __shared__ __align__(16) f16 wlds[4*8*4*64*8];   // 128 KB
    __shared__ __align__(16) f16 hbuf[MT*DSTR];
    __shared__ float part[4][16][2];
    __shared__ int lmax_s;
    const int tid = threadIdx.x;
    const int wave = tid>>6, lane = tid&63, lr = lane&15, quad = lane>>4;
    const int bid = blockIdx.x, hb = bid>>7, g = bid&127, pbid = bid^128;
    const int row0 = g*MT;
    const int xr = tid>>4, xc = tid&15;

    for (int i=tid;i<MT*DSTR;i+=256) hbuf[i] = (f16)0.f;
    if (tid < 64){
        int l = (lane<16) ? lengths[row0+lane] : 0;
        #pragma unroll
        for (int m=1;m<16;m<<=1){ int o = __shfl_xor(l, m, 64); l = (o>l)?o:l; }
        if (lane==0) lmax_s = l;
    }

    float xd[8][4];
    #pragma unroll
    for (int nt=0;nt<8;++nt){
        int n = (nt>>1)*256 + hb*128 + wave*32 + (nt&1)*16 + lr;
        #pragma unroll
        for (int r=0;r<4;++r) xd[nt][r] = xdec[(size_t)(row0+quad*4+r)*1024 + n];
    }
    float wpi_reg[2][2];
    #pragma unroll
    for (int a=0;a<2;++a)
        #pragma unroll
        for (int s=0;s<2;++s)
            wpi_reg[a][s] = Wpi[a*H_ + hb*128 + wave*32 + s*16 + lr];

    const f16x8* Wb = (const f16x8*)Wp + (size_t)((hb*4+wave)*8*DEC_KT)*64;
    f16x8 wreg[8][4];                        // own-half kts 0..3
    #pragma unroll
    for (int nt=0;nt<8;++nt)
        #pragma unroll
        for (int kt=0;kt<4;++kt)
            wreg[nt][kt] = Wb[(nt*DEC_KT + kt)*64 + lane];
    f16x8* wl = (f16x8*)wlds + (size_t)wave*(8*4*64);
    #pragma unroll
    for (int nt=0;nt<8;++nt)
        #pragma unroll
        for (int p=0;p<4;++p)
            wl[(nt*4 + p)*64 + lane] = Wb[(nt*DEC_KT + 4 + p)*64 + lane];

    float c_reg[8];
    #pragma unroll
    for (int i=0;i<8;++i) c_reg[i]=0.f;

    const int m_o = (tid>>1)&15, a_o = tid&1;
    const float bpi_o = bpi[a_o];
    const int len_o = (tid<32) ? lengths[row0+m_o] : 0;
    const size_t outbase = (size_t)(row0+m_o)*V_*2 + a_o;
    float own_prev = 0.f;

    __syncthreads();
    const int Lmax = lmax_s;

    for (int t=0;t<Lmax;++t){
        uint32_t f0 = (uint32_t)t;
        if (t > 0 && lane < 4) f0 = ld_u32((const uint32_t*)&flags[pbid*4 + lane]);
        f32x4 acc[8];
        #pragma unroll
        for (int nt=0;nt<8;++nt) acc[nt] = (f32x4){xd[nt][0],xd[nt][1],xd[nt][2],xd[nt][3]};
        #pragma unroll
        for (int kt=0;kt<4;++kt){
            f16x8 a = *(const f16x8*)&hbuf[lr*DSTR + kt*32 + quad*8];
            #pragma unroll
            for (int nt=0;nt<8;++nt) acc[nt] = MFMA(a, wreg[nt][kt], acc[nt]);
        }
        if (t > 0){
            f16x8 b0[8];
            #pragma unroll
            for (int nt=0;nt<8;++nt) b0[nt] = wl[(nt*4 + 0)*64 + lane];
            if (lane < 4){
                while (f0 < (uint32_t)t){
                    __builtin_amdgcn_s_sleep(1);
                    f0 = ld_u32((const uint32_t*)&flags[pbid*4 + lane]);
                }
            }
            const f16* src = ebuf + ((size_t)((t-1)&1)*256 + pbid)*2048 + lr*128 + quad*8;
            f16x8 a0,a1,a2,a3;
            bypass_ld4(a0,a1,a2,a3, src, src+32, src+64, src+96);
            #pragma unroll
            for (int nt=0;nt<8;++nt) acc[nt] = MFMA(a0, b0[nt], acc[nt]);
            #pragma unroll
            for (int nt=0;nt<8;++nt) acc[nt] = MFMA(a1, wl[(nt*4+1)*64+lane], acc[nt]);
            #pragma unroll
            for (int nt=0;nt<8;++nt) acc[nt] = MFMA(a2, wl[(nt*4+2)*64+lane], acc[nt]);
            #pragma unroll
            for (int nt=0;nt<8;++nt) acc[nt] = MFMA(a3, wl[(nt*4+3)*64+lane], acc[nt]);
            // delayed pi output for step t-1 (partner partials valid under flag>=t)
            if (hb == 0 && tid < 32){
                uint32_t pu = ld_u32((const uint32_t*)pbuf + ((size_t)((t-1)&1)*128 + g)*32 + tid);
                float v = own_prev + __uint_as_float(pu) + bpi_o;
                v = tanh_fast(v);
                out[outbase + (size_t)(t-1)*2] = ((t-1) < len_o) ? v : 0.f;
            }
        }
        __syncthreads();                     // B2
        float spi[4][2];
        #pragma unroll
        for (int r=0;r<4;++r){ spi[r][0]=0.f; spi[r][1]=0.f; }
        #pragma unroll
        for (int s=0;s<2;++s){
            #pragma unroll
            for (int r=0;r<4;++r){
                int idx = s*4 + r;
                float gi = acc[s][r],   gf = acc[2+s][r];
                float gg = acc[4+s][r], go = acc[6+s][r];
                float cn = sigf(gf)*c_reg[idx] + sigf(gi)*tanh_fast(gg);
                c_reg[idx] = cn;
                float hn = sigf(go)*tanh_fast(cn);
                hbuf[(quad*4+r)*DSTR + wave*32 + s*16 + lr] = (f16)hn;
                spi[r][0] += cn*wpi_reg[0][s];
                spi[r][1] += cn*wpi_reg[1][s];
            }
        }
        #pragma unroll
        for (int msk=1; msk<16; msk<<=1){
            #pragma unroll
            for (int r=0;r<4;++r){
                spi[r][0] += __shfl_xor(spi[r][0], msk, 64);
                spi[r][1] += __shfl_xor(spi[r][1], msk, 64);
            }
        }
        if (lr == 0){
            #pragma unroll
            for (int r=0;r<4;++r){
                part[wave][quad*4+r][0] = spi[r][0];
                part[wave][quad*4+r][1] = spi[r][1];
            }
        }
        __syncthreads();                     // B3: h_t + part visible
        {
            f16x8 h8 = *(const f16x8*)&hbuf[xr*DSTR + xc*8];
            f16* dst = ebuf + ((size_t)(t&1)*256 + bid)*2048 + xr*128 + xc*8;
            bypass_st(dst, h8);
        }
        if (tid < 32){
            float own4 = part[0][m_o][a_o]+part[1][m_o][a_o]+part[2][m_o][a_o]+part[3][m_o][a_o];
            if (hb == 1) st_u32((uint32_t*)pbuf + ((size_t)(t&1)*128 + g)*32 + tid,
                                __float_as_uint(own4));
            else         own_prev = own4;
        }
        vm_drain();                          // per-wave: ebuf(+pbuf) at coherence pt
        if (lane == 0) st_u32((uint32_t*)&flags[bid*4 + wave], (uint32_t)(t+1));
    }
    // epilogue: final pi output (step Lmax-1) + zero-fill t >= Lmax
    if (hb == 0 && tid < 32){
        uint32_t fv = ld_u32((const uint32_t*)&flags[pbid*4 + 0]);
        while (fv < (uint32_t)Lmax){
            __builtin_amdgcn_s_sleep(1);
            fv = ld_u32((const uint32_t*)&flags[pbid*4 + 0]);
        }
        uint32_t pu = ld_u32((const uint32_t*)pbuf + ((size_t)((Lmax-1)&1)*128 + g)*32 + tid);
        float v = own_prev + __uint_as_float(pu) + bpi_o;
        v = tanh_fast(v);
        out[outbase + (size_t)(Lmax-1)*2] = ((Lmax-1) < len_o) ? v : 0.f;
        for (int t=Lmax; t<V_; ++t) out[outbase + (size_t)t*2] = 0.f;
    }
}

extern "C" void kernel_launch(void* const* d_in, const int* in_sizes, int n_in,
                              void* d_out, int out_size, void* d_ws, size_t ws_size,
                              hipStream_t stream) {
    const float* state = (const float*)d_in[0];
    const int*   lengths=(const int*)d_in[1];
    const float* Wih1 = (const float*)d_in[2];
    const float* Whh1 = (const float*)d_in[3];
    const float* bih1 = (const float*)d_in[4];
    const float* bhh1 = (const float*)d_in[5];
    const float* W1   = (const float*)d_in[6];  const float* b1 = (const float*)d_in[7];
    const float* W2   = (const float*)d_in[8];  const float* b2 = (const float*)d_in[9];
    const float* W3   = (const float*)d_in[10]; const float* b3 = (const float*)d_in[11];
    const float* W4   = (const float*)d_in[12]; const float* b4 = (const float*)d_in[13];
    const float* Wih2 = (const float*)d_in[14]; const float* Whh2=(const float*)d_in[15];
    const float* bih2 = (const float*)d_in[16]; const float* bhh2=(const float*)d_in[17];
    const float* Wpi  = (const float*)d_in[18]; const float* bpi =(const float*)d_in[19];
    float* out = (float*)d_out;

    char* p = (char*)d_ws;
    auto alloc = [&](size_t bytes){ char* r = p; p += (bytes + 255) & ~(size_t)255; return r; };
    f16* WencP   = (f16*)alloc((size_t)2*4*8*ENC_KT*64*8*2);
    f16* WdecP   = (f16*)alloc((size_t)2*4*8*DEC_KT*64*8*2);
    f16* W1f     = (f16*)alloc((size_t)1024*256*2);
    f16* W2f     = (f16*)alloc((size_t)1024*1024*2);
    f16* W3f     = (f16*)alloc((size_t)512*1024*2);
    f16* W4f     = (f16*)alloc((size_t)256*512*2);
    f16* Wih2f   = (f16*)alloc((size_t)1024*256*2);
    float* biasE = (float*)alloc(1024*4);
    float* biasD = (float*)alloc(1024*4);
    f16* henc    = (f16*)alloc((size_t)2048*256*2);
    f16* act1    = (f16*)alloc((size_t)2048*1024*2);
    f16* act2    = (f16*)alloc((size_t)2048*1024*2);
    f16* act3    = (f16*)alloc((size_t)2048*512*2);
    f16* x4      = (f16*)alloc((size_t)2048*256*2);
    float* xdec  = (float*)alloc((size_t)2048*1024*4);
    f16* ebuf    = (f16*)alloc((size_t)2*256*2048*2);
    float* pbuf  = (float*)alloc((size_t)2*128*32*4);
    int* flags   = (int*)alloc((size_t)2048*4);   // [0:1024)=enc, [1024:2048)=dec (4 per block)

    hipMemsetAsync(flags, 0, 2048*4, stream);

    prepack_enc<<<(2*4*8*ENC_KT*64+255)/256,256,0,stream>>>(Whh1, Wih1, WencP);
    prepack_dec<<<(2*4*8*DEC_KT*64+255)/256,256,0,stream>>>(Whh2, WdecP);
    bias_kernel<<<4,256,0,stream>>>(bih1,bhh1,bih2,bhh2,biasE,biasD);
    convert_kernel<<<(1024*256+255)/256,256,0,stream>>>(W1, W1f, 1024*256);
    convert_kernel<<<(1024*1024+255)/256,256,0,stream>>>(W2, W2f, 1024*1024);
    convert_kernel<<<(512*1024+255)/256,256,0,stream>>>(W3, W3f, 512*1024);
    convert_kernel<<<(256*512+255)/256,256,0,stream>>>(W4, W4f, 256*512);
    convert_kernel<<<(1024*256+255)/256,256,0,stream>>>(Wih2, Wih2f, 1024*256);

    encoder_kernel<<<256,256,0,stream>>>(state, lengths, WencP, biasE, henc, ebuf, flags);

    gemm_kernel<true ,false><<<dim3(16,32),256,0,stream>>>(henc, W1f, b1, act1, 2048,1024,256);
    gemm_kernel<true ,false><<<dim3(16,32),256,0,stream>>>(act1, W2f, b2, act2, 2048,1024,1024);
    gemm_kernel<true ,false><<<dim3( 8,32),256,0,stream>>>(act2, W3f, b3, act3, 2048, 512,1024);
    gemm_kernel<true ,false><<<dim3( 4,32),256,0,stream>>>(act3, W4f, b4, x4,   2048, 256, 512);
    gemm_kernel<false,true ><<<dim3(16,32),256,0,stream>>>(x4, Wih2f, biasD, xdec, 2048,1024,256);

    decoder_kernel<<<256,256,0,stream>>>(lengths, WdecP, xdec, Wpi, bpi, out,
                                         ebuf, flags+1024, pbuf);
}